// Round 1
// baseline (227.945 us; speedup 1.0000x reference)
//
#include <hip/hip_runtime.h>
#include <hip/hip_bf16.h>
#include <stdint.h>

// GCN forward, collapsed to scalar form (W1:[1,16], W2:[16,1] are rank-1).
// R10: identical to R9 — resubmission to re-establish baseline + capture
// rocprof counters (previous round's bench failed with GPUAcquisitionTimeout;
// no counter evidence to justify an edit).
// R9 (on R8's fixed-capacity slot partition):
//  - k_part: LDS tile-sort staging. R8 stored each edge with a 4B random
//    write at an LDS-cursor position; per-block slot working set (76 KB x 64
//    blocks/XCD) thrashed L2 with partial lines. Now each 2048-edge tile is
//    counted, scanned, staged sorted-by-bucket in LDS, then written out as
//    bucket-contiguous runs (~168 B) at per-block cursors.
//  - k_scat/k_deg2: wave-per-segment, uint4 slot loads, 2 segments in
//    flight -> 8 independent val[] gathers per lane (R8 had 2; Occ 25->47%
//    did nothing, so the wall was per-thread MLP, not wave count).
// No global atomics (R2-R4: gfx950 global atomic RMW is memory-side, ~20G/s,
// WRITE_SIZE=E*32B regardless of privatization/scope). Dropout reproduces
// JAX partitionable threefry (split k_i=E(key,(0,i)); bits=o0^o1 of E(k,(0,j))).
// Requires N <= 131072 (NBMAX) and N < 2^21 (src fits 21 bits).

#define KEEP_P 0.4f
#define RANGE 2048
#define SHIFT 11
#define MASK 2047
#define BPC 512         // partition blocks
#define KS 32           // scatter slices (grid = KS x NB)
#define SEGS (BPC / KS) // 16 slot-segments per scatter block
#define NBMAX 64
#define TILE 2048       // edges per k_part tile
#define TILE4 (TILE / 4)

__host__ __device__ inline unsigned rotl32(unsigned v, int s) {
  return (v << s) | (v >> (32 - s));
}

__host__ __device__ inline void threefry2x32(unsigned key0, unsigned key1,
                                             unsigned x0, unsigned x1,
                                             unsigned& o0, unsigned& o1) {
  unsigned ks0 = key0, ks1 = key1, ks2 = key0 ^ key1 ^ 0x1BD11BDAu;
  unsigned v0 = x0 + ks0, v1 = x1 + ks1;
#define TF_R(r) { v0 += v1; v1 = rotl32(v1, r); v1 ^= v0; }
  TF_R(13) TF_R(15) TF_R(26) TF_R(6)
  v0 += ks1; v1 += ks2 + 1u;
  TF_R(17) TF_R(29) TF_R(16) TF_R(24)
  v0 += ks2; v1 += ks0 + 2u;
  TF_R(13) TF_R(15) TF_R(26) TF_R(6)
  v0 += ks0; v1 += ks1 + 3u;
  TF_R(17) TF_R(29) TF_R(16) TF_R(24)
  v0 += ks1; v1 += ks2 + 4u;
  TF_R(13) TF_R(15) TF_R(26) TF_R(6)
  v0 += ks2; v1 += ks0 + 5u;
#undef TF_R
  o0 = v0; o1 = v1;
}

__device__ inline float u01_from_bits(unsigned bits) {
  return __uint_as_float((bits >> 9) | 0x3f800000u) - 1.0f;
}

// ---- K1: slot partition with LDS tile-sort staging -------------------------
__global__ __launch_bounds__(256) void k_part(
    const int* __restrict__ src, const int* __restrict__ dst,
    unsigned* __restrict__ slots, unsigned* __restrict__ cnt,
    int NB, int CAP, int e4, int E) {
  __shared__ unsigned hist[NBMAX], scan_s[NBMAX + 1], off[NBMAX];
  __shared__ unsigned tbase[NBMAX], cur[NBMAX];
  __shared__ unsigned stage[TILE];
  __shared__ unsigned char stage_p[TILE];
  const int tid = threadIdx.x;
  const size_t blkbase = (size_t)blockIdx.x * NB;
  unsigned* myslots = slots + blkbase * CAP;
  for (int p = tid; p < NB; p += 256) cur[p] = (unsigned)(p * CAP);
  const int chunk = (e4 + BPC - 1) / BPC;
  const int j0 = blockIdx.x * chunk;
  const int j1 = min(j0 + chunk, e4);
  const int4* dst4 = reinterpret_cast<const int4*>(dst);
  const int4* src4 = reinterpret_cast<const int4*>(src);

  for (int t0 = j0; t0 < j1; t0 += TILE4) {
    __syncthreads();
    for (int p = tid; p < NB; p += 256) hist[p] = 0u;
    __syncthreads();
    // A: count this tile (hold dst in regs)
    const int ja = t0 + tid, jb = t0 + TILE4 / 2 + tid;
    const bool va = ja < j1 && tid < TILE4 / 2;
    const bool vb = jb < j1;
    int4 da, db;
    if (va) {
      da = dst4[ja];
      atomicAdd(&hist[(unsigned)da.x >> SHIFT], 1u);
      atomicAdd(&hist[(unsigned)da.y >> SHIFT], 1u);
      atomicAdd(&hist[(unsigned)da.z >> SHIFT], 1u);
      atomicAdd(&hist[(unsigned)da.w >> SHIFT], 1u);
    }
    if (vb) {
      db = dst4[jb];
      atomicAdd(&hist[(unsigned)db.x >> SHIFT], 1u);
      atomicAdd(&hist[(unsigned)db.y >> SHIFT], 1u);
      atomicAdd(&hist[(unsigned)db.z >> SHIFT], 1u);
      atomicAdd(&hist[(unsigned)db.w >> SHIFT], 1u);
    }
    __syncthreads();
    // B: scan
    if (tid == 0) {
      unsigned acc = 0;
      for (int p = 0; p < NB; ++p) { scan_s[p] = acc; acc += hist[p]; }
      scan_s[NB] = acc;
    }
    __syncthreads();
    for (int p = tid; p < NB; p += 256) {
      off[p] = scan_s[p];
      tbase[p] = cur[p];
      cur[p] += hist[p];
    }
    __syncthreads();
    // C: stage sorted-by-bucket
#define STAGE1(d, s) { unsigned ud = (unsigned)(d), us = (unsigned)(s); \
    unsigned p = ud >> SHIFT; unsigned pos = atomicAdd(&off[p], 1u); \
    stage[pos] = (ud & MASK) | (us << SHIFT); stage_p[pos] = (unsigned char)p; }
    if (va) {
      int4 sa = src4[ja];
      STAGE1(da.x, sa.x) STAGE1(da.y, sa.y) STAGE1(da.z, sa.z) STAGE1(da.w, sa.w)
    }
    if (vb) {
      int4 sb = src4[jb];
      STAGE1(db.x, sb.x) STAGE1(db.y, sb.y) STAGE1(db.z, sb.z) STAGE1(db.w, sb.w)
    }
#undef STAGE1
    __syncthreads();
    // D: write out bucket-contiguous runs
    const int tc = (int)scan_s[NB];
    for (int i = tid; i < tc; i += 256) {
      unsigned p = stage_p[i];
      myslots[tbase[p] + ((unsigned)i - scan_s[p])] = stage[i];
    }
  }
  __syncthreads();
  if (blockIdx.x == 0) {  // tail when E%4 != 0 (dead for E=6.4M)
    for (int t = e4 * 4 + tid; t < E; t += 256) {
      unsigned ud = (unsigned)dst[t], us = (unsigned)src[t];
      unsigned p = ud >> SHIFT;
      unsigned pos = atomicAdd(&cur[p], 1u);
      myslots[pos] = (ud & MASK) | (us << SHIFT);
    }
  }
  __syncthreads();
  for (int p = tid; p < NB; p += 256)
    cnt[blkbase + p] = cur[p] - (unsigned)(p * CAP);
}

// ---- K2: degree from slots, wave-per-segment, uint4 loads ------------------
__global__ __launch_bounds__(256) void k_deg2(
    const unsigned* __restrict__ slots, const unsigned* __restrict__ cnt,
    unsigned short* __restrict__ part16, int NB, int CAP) {
  __shared__ unsigned bins[RANGE / 2];  // 4 KB, u16-packed
  const int tid = threadIdx.x, w = tid >> 6, lane = tid & 63;
  const int p = blockIdx.y, kd = blockIdx.x;
  for (int i = tid; i < RANGE / 2; i += 256) bins[i] = 0u;
  __syncthreads();
  const int b0 = kd * SEGS;
#define DEG_ONE(v) { unsigned r = (v) & MASK; \
    atomicAdd(&bins[r >> 1], 1u << ((r & 1) * 16)); }
  for (int q = 0; q < 4; q += 2) {
    const int bA = b0 + w + 4 * q, bB = b0 + w + 4 * (q + 1);
    const int lA = cnt[(size_t)bA * NB + p];
    const int lB = cnt[(size_t)bB * NB + p];
    const unsigned* eA = slots + ((size_t)bA * NB + p) * CAP;
    const unsigned* eB = slots + ((size_t)bB * NB + p) * CAP;
    const int lmax = lA > lB ? lA : lB;
    for (int base = 4 * lane; base < lmax; base += 256) {
      if (base + 4 <= lA) {
        uint4 av = *reinterpret_cast<const uint4*>(eA + base);
        DEG_ONE(av.x) DEG_ONE(av.y) DEG_ONE(av.z) DEG_ONE(av.w)
      } else {
        for (int k = base; k < lA; ++k) DEG_ONE(eA[k])
      }
      if (base + 4 <= lB) {
        uint4 bv = *reinterpret_cast<const uint4*>(eB + base);
        DEG_ONE(bv.x) DEG_ONE(bv.y) DEG_ONE(bv.z) DEG_ONE(bv.w)
      } else {
        for (int k = base; k < lB; ++k) DEG_ONE(eB[k])
      }
    }
  }
#undef DEG_ONE
  __syncthreads();
  unsigned* my32 = (unsigned*)(part16 + ((size_t)kd * gridDim.y + p) * RANGE);
  for (int i = tid; i < RANGE / 2; i += 256) my32[i] = bins[i];
}

// ---- K3: reduce deg partials -> dinv; dropout1 -> y ------------------------
__global__ __launch_bounds__(256) void k_node1(
    const float* __restrict__ x, const unsigned short* __restrict__ part16,
    float* __restrict__ dinv, float* __restrict__ y,
    int NB, int n, unsigned k1a, unsigned k1b) {
  int i = blockIdx.x * blockDim.x + threadIdx.x;
  if (i >= n) return;
  const int p = i >> SHIFT, r = i & MASK;
  unsigned d = 0;
  for (int b = 0; b < KS; ++b)
    d += part16[((size_t)b * NB + p) * RANGE + r];
  float di = (d > 0) ? (1.0f / sqrtf((float)d)) : 0.0f;
  dinv[i] = di;
  unsigned o0, o1;
  threefry2x32(k1a, k1b, 0u, (unsigned)i, o0, o1);
  float u = u01_from_bits(o0 ^ o1);   // partitionable 32-bit bits = out0 ^ out1
  float xd = (u < KEEP_P) ? (x[i] / KEEP_P) : 0.0f;
  y[i] = xd * di;
}

// ---- K4/K6: binned scatter, wave-per-segment, uint4 + 8-deep gathers -------
__global__ __launch_bounds__(256) void k_scat(
    const unsigned* __restrict__ slots, const unsigned* __restrict__ cnt,
    const float* __restrict__ val, float* __restrict__ part,
    int NB, int CAP) {
  __shared__ float bins[RANGE];  // 8 KB
  const int tid = threadIdx.x, w = tid >> 6, lane = tid & 63;
  const int p = blockIdx.y, ks = blockIdx.x;
  for (int i = tid; i < RANGE; i += 256) bins[i] = 0.0f;
  __syncthreads();
  const int b0 = ks * SEGS;
  for (int q = 0; q < 4; q += 2) {
    const int bA = b0 + w + 4 * q, bB = b0 + w + 4 * (q + 1);
    const int lA = cnt[(size_t)bA * NB + p];
    const int lB = cnt[(size_t)bB * NB + p];
    const unsigned* eA = slots + ((size_t)bA * NB + p) * CAP;
    const unsigned* eB = slots + ((size_t)bB * NB + p) * CAP;
    const int lmax = lA > lB ? lA : lB;
    for (int base = 4 * lane; base < lmax; base += 256) {
      const bool fA = base + 4 <= lA, fB = base + 4 <= lB;
      if (fA && fB) {
        uint4 av = *reinterpret_cast<const uint4*>(eA + base);
        uint4 bv = *reinterpret_cast<const uint4*>(eB + base);
        float a0 = val[av.x >> SHIFT], a1 = val[av.y >> SHIFT];
        float a2 = val[av.z >> SHIFT], a3 = val[av.w >> SHIFT];
        float c0 = val[bv.x >> SHIFT], c1 = val[bv.y >> SHIFT];
        float c2 = val[bv.z >> SHIFT], c3 = val[bv.w >> SHIFT];
        atomicAdd(&bins[av.x & MASK], a0);
        atomicAdd(&bins[av.y & MASK], a1);
        atomicAdd(&bins[av.z & MASK], a2);
        atomicAdd(&bins[av.w & MASK], a3);
        atomicAdd(&bins[bv.x & MASK], c0);
        atomicAdd(&bins[bv.y & MASK], c1);
        atomicAdd(&bins[bv.z & MASK], c2);
        atomicAdd(&bins[bv.w & MASK], c3);
      } else {
        if (fA) {
          uint4 av = *reinterpret_cast<const uint4*>(eA + base);
          float a0 = val[av.x >> SHIFT], a1 = val[av.y >> SHIFT];
          float a2 = val[av.z >> SHIFT], a3 = val[av.w >> SHIFT];
          atomicAdd(&bins[av.x & MASK], a0);
          atomicAdd(&bins[av.y & MASK], a1);
          atomicAdd(&bins[av.z & MASK], a2);
          atomicAdd(&bins[av.w & MASK], a3);
        } else {
          for (int k = base; k < lA; ++k) {
            unsigned v = eA[k];
            atomicAdd(&bins[v & MASK], val[v >> SHIFT]);
          }
        }
        if (fB) {
          uint4 bv = *reinterpret_cast<const uint4*>(eB + base);
          float c0 = val[bv.x >> SHIFT], c1 = val[bv.y >> SHIFT];
          float c2 = val[bv.z >> SHIFT], c3 = val[bv.w >> SHIFT];
          atomicAdd(&bins[bv.x & MASK], c0);
          atomicAdd(&bins[bv.y & MASK], c1);
          atomicAdd(&bins[bv.z & MASK], c2);
          atomicAdd(&bins[bv.w & MASK], c3);
        } else {
          for (int k = base; k < lB; ++k) {
            unsigned v = eB[k];
            atomicAdd(&bins[v & MASK], val[v >> SHIFT]);
          }
        }
      }
    }
  }
  __syncthreads();
  float* my = part + ((size_t)ks * NB + p) * RANGE;
  for (int i = tid; i < RANGE; i += 256) my[i] = bins[i];
}

// ---- K5: reduce s partials; layer1 epilogue + relu + dropout2 + W2 dot -----
__global__ __launch_bounds__(256) void k_node2(
    const float* __restrict__ part, const float* __restrict__ dinv,
    const float* __restrict__ W1, const float* __restrict__ b1,
    const float* __restrict__ W2, float* __restrict__ z2,
    int NB, int n, unsigned k2a, unsigned k2b) {
  int i = blockIdx.x * blockDim.x + threadIdx.x;
  if (i >= n) return;
  const int p = i >> SHIFT, r = i & MASK;
  float s = 0.0f;
  for (int b = 0; b < KS; ++b)
    s += part[((size_t)b * NB + p) * RANGE + r];
  float t = s * dinv[i];
  float z = 0.0f;
  unsigned base = (unsigned)i * 16u;
#pragma unroll
  for (int c = 0; c < 16; ++c) {
    float h = W1[c] * t + b1[c];
    h = fmaxf(h, 0.0f);
    unsigned o0, o1;
    threefry2x32(k2a, k2b, 0u, base + (unsigned)c, o0, o1);
    float u = u01_from_bits(o0 ^ o1);
    float hd = (u < KEEP_P) ? (h / KEEP_P) : 0.0f;
    z += hd * W2[c];
  }
  z2[i] = z * dinv[i];   // dinv[dst] factor applied in k_final
}

// ---- K7: final combine: out = b2 + dinv * sum(partials) --------------------
__global__ __launch_bounds__(256) void k_final(
    const float* __restrict__ part, const float* __restrict__ dinv,
    const float* __restrict__ b2, float* __restrict__ out,
    int NB, int n) {
  int i = blockIdx.x * blockDim.x + threadIdx.x;
  if (i >= n) return;
  const int p = i >> SHIFT, r = i & MASK;
  float s = 0.0f;
  for (int b = 0; b < KS; ++b)
    s += part[((size_t)b * NB + p) * RANGE + r];
  out[i] = b2[0] + dinv[i] * s;
}

extern "C" void kernel_launch(void* const* d_in, const int* in_sizes, int n_in,
                              void* d_out, int out_size, void* d_ws, size_t ws_size,
                              hipStream_t stream) {
  const float* x  = (const float*)d_in[0];
  const int* edge = (const int*)d_in[1];   // [2, E] int32
  const float* W1 = (const float*)d_in[2]; // [1,16]
  const float* b1 = (const float*)d_in[3]; // [16]
  const float* W2 = (const float*)d_in[4]; // [16,1]
  const float* b2 = (const float*)d_in[5]; // [1]
  float* out = (float*)d_out;              // [N,1] f32

  const int N = in_sizes[0];
  const int E = in_sizes[1] / 2;
  const int* src = edge;
  const int* dst = edge + E;

  const int NP = (N + 255) & ~255;
  const int NB = (N + RANGE - 1) / RANGE;   // 49 for N=100K (<= NBMAX)

  // ws layout: [slots NB*BPC*CAP u32][cnt BPC*NB u32]
  //            [part KS*NB*RANGE f32 (aliases deg u16 partials)][dinv][y][z2]
  const size_t cnt_sz  = (size_t)BPC * NB * 4;
  const size_t part_sz = (size_t)KS * NB * RANGE * 4;
  const size_t small_sz = (size_t)3 * NP * 4;
  size_t fixed = cnt_sz + part_sz + small_sz + 512;
  size_t avail = ws_size > fixed ? ws_size - fixed : 0;
  int CAP = (int)(avail / ((size_t)NB * BPC * 4));
  CAP &= ~3;                  // 16B-aligned slot starts for uint4 loads
  if (CAP > 512) CAP = 512;   // 16+ sigma over mean 256, plenty
  if (CAP < 288) CAP = 288;   // ws guard (should not trigger)

  char* w = (char*)d_ws;
  unsigned* slots = (unsigned*)w;        w += (size_t)NB * BPC * CAP * 4;
  unsigned* cnt   = (unsigned*)w;        w += cnt_sz;
  w = (char*)(((uintptr_t)w + 255) & ~(uintptr_t)255);
  float* part_f = (float*)w;
  unsigned short* part16 = (unsigned short*)w;  // aliased (deg phase ends first)
  w += part_sz;
  float* dinv = (float*)w;
  float* y    = dinv + NP;
  float* z2   = y + NP;

  // Dropout keys: foldlike split(key(42)) under partitionable threefry.
  unsigned k1a, k1b, k2a, k2b;
  threefry2x32(0u, 42u, 0u, 0u, k1a, k1b);
  threefry2x32(0u, 42u, 0u, 1u, k2a, k2b);

  const int e4 = E >> 2;
  const int gN = (N + 255) / 256;

  k_part <<<BPC, 256, 0, stream>>>(src, dst, slots, cnt, NB, CAP, e4, E);
  k_deg2 <<<dim3(KS, NB), 256, 0, stream>>>(slots, cnt, part16, NB, CAP);
  k_node1<<<gN, 256, 0, stream>>>(x, part16, dinv, y, NB, N, k1a, k1b);
  k_scat <<<dim3(KS, NB), 256, 0, stream>>>(slots, cnt, y, part_f, NB, CAP);
  k_node2<<<gN, 256, 0, stream>>>(part_f, dinv, W1, b1, W2, z2, NB, N, k2a, k2b);
  k_scat <<<dim3(KS, NB), 256, 0, stream>>>(slots, cnt, z2, part_f, NB, CAP);
  k_final<<<gN, 256, 0, stream>>>(part_f, dinv, b2, out, NB, N);
}